// Round 7
// baseline (347.589 us; speedup 1.0000x reference)
//
#include <hip/hip_runtime.h>
#include <hip/hip_fp16.h>

// GraphSAGE 2-layer encoder — lean build: single-pass partition into 64-node
// buckets, per-bucket LDS sort fused into the gather, 128-row dual_gemm.
// R6 postmortem: gather (2x55us) is near its structural floor (E*128B
// compulsory traffic at the ~3.3TB/s random-128B fabric rate); the ~200us of
// build+gemm kernels is now the bigger pool. R7 removes prehist's duplicate
// histogram pass, local_csr, sorted_src/rowptr traffic, and halves gemm
// W-staging traffic.

#define DIM 64
#define BN 64                 // nodes per bucket (dst >> 6)
#define MAXBUCK 2048          // LDS array bound (nbuck = 1563)
#define CHUNK 8192            // edges per hist/partition block
#define GCAP 2048             // LDS edge capacity per gather block (mean ~1024)

__device__ inline void fma4(float4& acc, float s, const float4 w) {
    acc.x = fmaf(s, w.x, acc.x); acc.y = fmaf(s, w.y, acc.y);
    acc.z = fmaf(s, w.z, acc.z); acc.w = fmaf(s, w.w, acc.w);
}

// accumulate 8 halves (loaded as float4 bit-pattern) into acc[8]
__device__ inline void addh8(float* acc, float4 raw) {
    const __half2* hp = (const __half2*)&raw;
#pragma unroll
    for (int k = 0; k < 4; ++k) {
        float2 f = __half22float2(hp[k]);
        acc[2 * k]     += f.x;
        acc[2 * k + 1] += f.y;
    }
}

// ---- per-chunk histogram -> Hmat[block][bucket] (+ global totals) ----
__global__ __launch_bounds__(256) void hist_kernel(const int* __restrict__ dst,
                                                   int* __restrict__ Hmat,
                                                   int* __restrict__ ghist,
                                                   int nE, int nbuck) {
    __shared__ int hist[MAXBUCK];
    const int t = threadIdx.x;
    for (int k = t; k < nbuck; k += 256) hist[k] = 0;
    __syncthreads();
    const int base = blockIdx.x * CHUNK;
    const int end = min(nE, base + CHUNK);
    for (int i = base + t; i < end; i += 256)
        atomicAdd(&hist[dst[i] >> 6], 1);
    __syncthreads();
    int* row = Hmat + (size_t)blockIdx.x * nbuck;
    for (int k = t; k < nbuck; k += 256) {
        int h = hist[k];
        row[k] = h;
        if (h) atomicAdd(&ghist[k], h);
    }
}

// ---- exclusive scan of bucket totals (1 block, 1024 thr, ping-pong) ----
__global__ __launch_bounds__(1024) void scan_kernel(const int* __restrict__ ghist,
                                                    int* __restrict__ boff, int nbuck) {
    __shared__ int sa[2048], sb[2048];
    const int t = threadIdx.x;
    int v0 = (t < nbuck) ? ghist[t] : 0;
    int v1 = (t + 1024 < nbuck) ? ghist[t + 1024] : 0;
    sa[t] = v0; sa[t + 1024] = v1;
    __syncthreads();
    int* in = sa; int* out = sb;
    for (int d = 1; d < 2048; d <<= 1) {
        out[t] = in[t] + ((t >= d) ? in[t - d] : 0);
        int i2 = t + 1024;
        out[i2] = in[i2] + ((i2 >= d) ? in[i2 - d] : 0);
        __syncthreads();
        int* tmp = in; in = out; out = tmp;
    }
    if (t < nbuck) boff[t] = in[t] - v0;
    if (t + 1024 < nbuck) boff[t + 1024] = in[t + 1024] - v1;
    if (t == 0) boff[nbuck] = in[2047];
}

// ---- convert Hmat counts into per-(block,bucket) write bases (in place) ----
__global__ __launch_bounds__(256) void bases_kernel(int* __restrict__ Hmat,
                                                    const int* __restrict__ boff,
                                                    int nbuck, int nblk) {
    int k = blockIdx.x * 256 + threadIdx.x;
    if (k >= nbuck) return;
    int run = boff[k];
    for (int j = 0; j < nblk; ++j) {
        int* p = Hmat + (size_t)j * nbuck + k;
        int h = *p;
        *p = run;
        run += h;
    }
}

// ---- single-pass partition: scatter packed (src<<6 | dst&63) ----
__global__ __launch_bounds__(256) void partition_kernel(const int* __restrict__ src,
                                                        const int* __restrict__ dst,
                                                        const int* __restrict__ Hmat,
                                                        unsigned* __restrict__ P,
                                                        int nE, int nbuck) {
    __shared__ int cur[MAXBUCK];
    const int t = threadIdx.x;
    const int* row = Hmat + (size_t)blockIdx.x * nbuck;
    for (int k = t; k < nbuck; k += 256) cur[k] = row[k];
    __syncthreads();
    const int base = blockIdx.x * CHUNK;
    const int end = min(nE, base + CHUNK);
    for (int i = base + t; i < end; i += 256) {
        int d = dst[i];
        int bk = d >> 6;
        int pos = atomicAdd(&cur[bk], 1);
        P[pos] = ((unsigned)src[i] << 6) | (unsigned)(d & 63);
    }
}

// ---- dual GEMM: A(fp16) = H@Wl ; Dbuf(fp32) = H@Wr + bias ----
// 128 rows/block in 2 phases sharing one W staging (halves W traffic).
__global__ __launch_bounds__(256) void dual_gemm(const float* __restrict__ H,
                                                 const float* __restrict__ Wl,
                                                 const float* __restrict__ Wr,
                                                 const float* __restrict__ bias,
                                                 __half* __restrict__ A,
                                                 float* __restrict__ Dbuf, int n) {
    __shared__ float wsl[4096];
    __shared__ float wsr[4096];
    __shared__ float hs[64 * 68];
    __shared__ float bs[64];
    const int t = threadIdx.x;
    for (int i = t * 4; i < 4096; i += 1024) {
        *(float4*)&wsl[i] = *(const float4*)&Wl[i];
        *(float4*)&wsr[i] = *(const float4*)&Wr[i];
    }
    if (t < 16) *(float4*)&bs[t * 4] = *(const float4*)&bias[t * 4];
    const int dg = t & 15;
    const int r0 = t >> 4;
    for (int ph = 0; ph < 2; ++ph) {
        const int base = blockIdx.x * 128 + ph * 64;
        if (base >= n) break;
        __syncthreads();   // W ready (ph0) / previous phase's hs reads done
        for (int p = 0; p < 4; ++p) {
            int idx = t + p * 256;
            int r = idx >> 4, c4 = idx & 15;
            int row = base + r;
            if (row < n)
                *(float4*)&hs[r * 68 + c4 * 4] = *(const float4*)&H[(size_t)row * 64 + c4 * 4];
        }
        __syncthreads();
        float4 accl[4] = {{0,0,0,0},{0,0,0,0},{0,0,0,0},{0,0,0,0}};
        float4 accr[4] = {{0,0,0,0},{0,0,0,0},{0,0,0,0},{0,0,0,0}};
#pragma unroll 4
        for (int kq = 0; kq < 16; ++kq) {
            float4 wl[4], wr[4];
#pragma unroll
            for (int i = 0; i < 4; ++i) {
                wl[i] = *(const float4*)&wsl[(kq * 4 + i) * 64 + dg * 4];
                wr[i] = *(const float4*)&wsr[(kq * 4 + i) * 64 + dg * 4];
            }
#pragma unroll
            for (int p = 0; p < 4; ++p) {
                float4 hv = *(const float4*)&hs[(r0 + p * 16) * 68 + kq * 4];
                fma4(accl[p], hv.x, wl[0]); fma4(accl[p], hv.y, wl[1]);
                fma4(accl[p], hv.z, wl[2]); fma4(accl[p], hv.w, wl[3]);
                fma4(accr[p], hv.x, wr[0]); fma4(accr[p], hv.y, wr[1]);
                fma4(accr[p], hv.z, wr[2]); fma4(accr[p], hv.w, wr[3]);
            }
        }
        float4 b4 = *(const float4*)&bs[dg * 4];
#pragma unroll
        for (int p = 0; p < 4; ++p) {
            int row = base + r0 + p * 16;
            if (row < n) {
                union { __half2 h[2]; float2 f; } u;
                u.h[0] = __floats2half2_rn(accl[p].x, accl[p].y);
                u.h[1] = __floats2half2_rn(accl[p].z, accl[p].w);
                *(float2*)&A[(size_t)row * 64 + dg * 4] = u.f;
                float4 d;
                d.x = accr[p].x + b4.x; d.y = accr[p].y + b4.y;
                d.z = accr[p].z + b4.z; d.w = accr[p].w + b4.w;
                *(float4*)&Dbuf[(size_t)row * 64 + dg * 4] = d;
            }
        }
    }
}

// ---- gather with fused in-LDS bucket sort ----
// One block per 64-node bucket: LDS hist + wave scan + scatter sort of the
// bucket's packed edges, then 8-lane-per-row register-accumulate gather and
// fused epilogue out = act(mean + D). Spill path for oversized buckets.
template <bool RELU>
__global__ __launch_bounds__(256) void gather_sort_combine(const __half* __restrict__ A,
                                                           const float* __restrict__ Dbuf,
                                                           const int* __restrict__ boff,
                                                           const unsigned* __restrict__ P,
                                                           int* __restrict__ spill,
                                                           float* __restrict__ out, int n) {
    __shared__ int hist[BN];
    __shared__ int rstart[BN];
    __shared__ int cur[BN];
    __shared__ int lsrc[GCAP];
    const int t = threadIdx.x;
    const int b = blockIdx.x;
    if (t < BN) hist[t] = 0;
    __syncthreads();
    const int start = boff[b], end = boff[b + 1];
    const int m = end - start;
    for (int i = start + t; i < end; i += 256)
        atomicAdd(&hist[P[i] & 63], 1);
    __syncthreads();
    if (t < 64) {   // wave 0: exclusive scan of 64 counts via shuffles
        int v = hist[t];
        int s = v;
#pragma unroll
        for (int d = 1; d < 64; d <<= 1) {
            int u = __shfl_up(s, d);
            if (t >= d) s += u;
        }
        rstart[t] = s - v;
        cur[t] = s - v;
    }
    __syncthreads();
    int* list = (m <= GCAP) ? (int*)lsrc : (spill + start);
    for (int i = start + t; i < end; i += 256) {
        unsigned p = P[i];
        int pos = atomicAdd(&cur[p & 63], 1);
        list[pos] = (int)(p >> 6);
    }
    __syncthreads();
    const int dg = t & 7;
    const size_t doff = (size_t)dg * 8;
    for (int pass = 0; pass < 2; ++pass) {
        const int r = pass * 32 + (t >> 3);
        const int node = b * BN + r;
        if (node >= n) continue;
        const int c = hist[r];
        const int* sp = list + rstart[r];
        float acc[8] = {0.f, 0.f, 0.f, 0.f, 0.f, 0.f, 0.f, 0.f};
        int j = 0;
        for (; j + 4 <= c; j += 4) {
            int e0 = sp[j + 0], e1 = sp[j + 1], e2 = sp[j + 2], e3 = sp[j + 3];
            float4 r0 = *(const float4*)&A[(size_t)e0 * 64 + doff];
            float4 r1 = *(const float4*)&A[(size_t)e1 * 64 + doff];
            float4 r2 = *(const float4*)&A[(size_t)e2 * 64 + doff];
            float4 r3 = *(const float4*)&A[(size_t)e3 * 64 + doff];
            addh8(acc, r0); addh8(acc, r1); addh8(acc, r2); addh8(acc, r3);
        }
        for (; j < c; ++j) {
            float4 rr = *(const float4*)&A[(size_t)sp[j] * 64 + doff];
            addh8(acc, rr);
        }
        const float inv = 1.0f / fmaxf((float)c, 1.0f);
        float4 d0 = *(const float4*)&Dbuf[(size_t)node * 64 + doff];
        float4 d1 = *(const float4*)&Dbuf[(size_t)node * 64 + doff + 4];
        float4 o0, o1;
        o0.x = fmaf(acc[0], inv, d0.x); o0.y = fmaf(acc[1], inv, d0.y);
        o0.z = fmaf(acc[2], inv, d0.z); o0.w = fmaf(acc[3], inv, d0.w);
        o1.x = fmaf(acc[4], inv, d1.x); o1.y = fmaf(acc[5], inv, d1.y);
        o1.z = fmaf(acc[6], inv, d1.z); o1.w = fmaf(acc[7], inv, d1.w);
        if (RELU) {
            o0.x = fmaxf(o0.x, 0.f); o0.y = fmaxf(o0.y, 0.f);
            o0.z = fmaxf(o0.z, 0.f); o0.w = fmaxf(o0.w, 0.f);
            o1.x = fmaxf(o1.x, 0.f); o1.y = fmaxf(o1.y, 0.f);
            o1.z = fmaxf(o1.z, 0.f); o1.w = fmaxf(o1.w, 0.f);
        }
        *(float4*)&out[(size_t)node * 64 + doff] = o0;
        *(float4*)&out[(size_t)node * 64 + doff + 4] = o1;
    }
}

extern "C" void kernel_launch(void* const* d_in, const int* in_sizes, int n_in,
                              void* d_out, int out_size, void* d_ws, size_t ws_size,
                              hipStream_t stream) {
    const float* x   = (const float*)d_in[0];
    const int*   ei  = (const int*)d_in[1];
    const float* w1l = (const float*)d_in[2];
    const float* b1l = (const float*)d_in[3];
    const float* w1r = (const float*)d_in[4];
    const float* w2l = (const float*)d_in[5];
    const float* b2l = (const float*)d_in[6];
    const float* w2r = (const float*)d_in[7];
    float* out = (float*)d_out;

    const int N = in_sizes[0] / DIM;   // 100000
    const int E = in_sizes[1] / 2;     // 1600000
    const int* src = ei;
    const int* dst = ei + E;
    const int nbuck = (N + BN - 1) / BN;           // 1563
    const int pb = (E + CHUNK - 1) / CHUNK;        // 196

    // ws: ghist[nbuck] | boff[nbuck+1] | Hmat[pb*nbuck] | P[E] | spill[E] |
    //     (align 16) A_fp16[N*64] | D[N*64]
    int* ghist = (int*)d_ws;
    int* boff = ghist + nbuck;
    int* Hmat = boff + nbuck + 1;
    unsigned* P = (unsigned*)(Hmat + (size_t)pb * nbuck);
    int* spill = (int*)(P + E);
    uintptr_t ap = (uintptr_t)(spill + E);
    ap = (ap + 15) & ~(uintptr_t)15;
    __half* A = (__half*)ap;
    float* D = (float*)(A + (size_t)N * DIM);
    float* h1 = out;                    // layer-1 output reuses d_out

    const int gb = (N + 127) / 128;                // 782

    // ---- build ----
    hipMemsetAsync(ghist, 0, nbuck * sizeof(int), stream);
    hist_kernel<<<pb, 256, 0, stream>>>(dst, Hmat, ghist, E, nbuck);
    scan_kernel<<<1, 1024, 0, stream>>>(ghist, boff, nbuck);
    bases_kernel<<<(nbuck + 255) / 256, 256, 0, stream>>>(Hmat, boff, nbuck, pb);
    partition_kernel<<<pb, 256, 0, stream>>>(src, dst, Hmat, P, E, nbuck);

    // ---- layer 1 ----
    dual_gemm<<<gb, 256, 0, stream>>>(x, w1l, w1r, b1l, A, D, N);
    gather_sort_combine<true><<<nbuck, 256, 0, stream>>>(A, D, boff, P, spill, h1, N);

    // ---- layer 2 ----
    dual_gemm<<<gb, 256, 0, stream>>>(h1, w2l, w2r, b2l, A, D, N);
    gather_sort_combine<false><<<nbuck, 256, 0, stream>>>(A, D, boff, P, spill, out, N);
}

// Round 8
// 290.119 us; speedup vs baseline: 1.1981x; 1.1981x over previous
//
#include <hip/hip_runtime.h>
#include <hip/hip_fp16.h>

// GraphSAGE 2-layer encoder — R8.
// Measured-good pieces: R6-style build (prehist + scan + atomic-reserve
// partition), R7 gather with fused in-LDS bucket sort (sort measured free:
// 54.9us vs 54.7us presorted). New: layer-1 dual_gemm fused into the
// partition dispatch (independent work, branch on blockIdx), and fp16 for
// the D (self-path) and h1 (layer-1 output) intermediates.
// R7 regression root cause (logged): bases_kernel was a 196-long serial
// dependent global RMW chain on 7 blocks — latency-bound; reverted.

#define DIM 64
#define BN 64                 // nodes per bucket (dst >> 6)
#define MAXBUCK 2048          // LDS bound (nbuck = 1563)
#define CHUNK 8192            // edges per hist/partition block
#define GCAP 2048             // LDS edge capacity per gather block (mean ~1024)
#define GEMM_SMEM 12608       // floats: wsl 4096 | wsr 4096 | hs 4352 | bs 64

__device__ inline void fma4(float4& acc, float s, const float4 w) {
    acc.x = fmaf(s, w.x, acc.x); acc.y = fmaf(s, w.y, acc.y);
    acc.z = fmaf(s, w.z, acc.z); acc.w = fmaf(s, w.w, acc.w);
}

// accumulate 8 halves (float4 bit-pattern) into acc[8]
__device__ inline void addh8(float* acc, float4 raw) {
    const __half2* hp = (const __half2*)&raw;
#pragma unroll
    for (int k = 0; k < 4; ++k) {
        float2 f = __half22float2(hp[k]);
        acc[2 * k]     += f.x;
        acc[2 * k + 1] += f.y;
    }
}

// ---- pre-histogram: global bucket counts ----
__global__ __launch_bounds__(256) void prehist_kernel(const int* __restrict__ dst,
                                                      int* __restrict__ ghist,
                                                      int nE, int nbuck) {
    __shared__ int hist[MAXBUCK];
    const int t = threadIdx.x;
    for (int k = t; k < nbuck; k += 256) hist[k] = 0;
    __syncthreads();
    const int base = blockIdx.x * CHUNK;
    const int end = min(nE, base + CHUNK);
    for (int i = base + t; i < end; i += 256)
        atomicAdd(&hist[dst[i] >> 6], 1);
    __syncthreads();
    for (int k = t; k < nbuck; k += 256)
        if (hist[k]) atomicAdd(&ghist[k], hist[k]);
}

// ---- exclusive scan of bucket totals (1 block, up to 2048) -> boff, gcur ----
__global__ __launch_bounds__(1024) void scan_kernel(const int* __restrict__ ghist,
                                                    int* __restrict__ boff,
                                                    int* __restrict__ gcur, int nbuck) {
    __shared__ int sa[2048], sb[2048];
    const int t = threadIdx.x;
    int v0 = (t < nbuck) ? ghist[t] : 0;
    int v1 = (t + 1024 < nbuck) ? ghist[t + 1024] : 0;
    sa[t] = v0; sa[t + 1024] = v1;
    __syncthreads();
    int* in = sa; int* out = sb;
    for (int d = 1; d < 2048; d <<= 1) {
        out[t] = in[t] + ((t >= d) ? in[t - d] : 0);
        int i2 = t + 1024;
        out[i2] = in[i2] + ((i2 >= d) ? in[i2 - d] : 0);
        __syncthreads();
        int* tmp = in; in = out; out = tmp;
    }
    if (t < nbuck) { int e = in[t] - v0; boff[t] = e; gcur[t] = e; }
    if (t + 1024 < nbuck) { int e = in[t + 1024] - v1; boff[t + 1024] = e; gcur[t + 1024] = e; }
    if (t == 0) boff[nbuck] = in[2047];
}

// ---- staging helpers: 64 rows of H into hs (fp32, stride 68) ----
__device__ inline void stage_rows(float* hs, const float* H, int base, int n, int t) {
    for (int p = 0; p < 4; ++p) {
        int idx = t + p * 256;          // float4 chunks
        int r = idx >> 4, c4 = idx & 15;
        int row = base + r;
        if (row < n)
            *(float4*)&hs[r * 68 + c4 * 4] = *(const float4*)&H[(size_t)row * 64 + c4 * 4];
    }
}
__device__ inline void stage_rows(float* hs, const __half* H, int base, int n, int t) {
    for (int p = 0; p < 2; ++p) {
        int idx = t + p * 256;          // half8 chunks (512 total)
        int r = idx >> 3, c8 = idx & 7;
        int row = base + r;
        if (row < n) {
            float4 raw = *(const float4*)&H[(size_t)row * 64 + c8 * 8];
            const __half2* hp = (const __half2*)&raw;
            float2 f0 = __half22float2(hp[0]);
            float2 f1 = __half22float2(hp[1]);
            float2 f2 = __half22float2(hp[2]);
            float2 f3 = __half22float2(hp[3]);
            float* d = &hs[r * 68 + c8 * 8];
            *(float4*)d       = make_float4(f0.x, f0.y, f1.x, f1.y);
            *(float4*)(d + 4) = make_float4(f2.x, f2.y, f3.x, f3.y);
        }
    }
}

// ---- dual GEMM body: A(fp16) = H@Wl ; D(fp16) = H@Wr + bias ----
// 128 rows per bid in 2 phases sharing one W staging.
template <typename InT>
__device__ void gemm_body(int bid, float* smem,
                          const InT* __restrict__ H,
                          const float* __restrict__ Wl, const float* __restrict__ Wr,
                          const float* __restrict__ bias,
                          __half* __restrict__ A, __half* __restrict__ Dbuf, int n) {
    float* wsl = smem;
    float* wsr = smem + 4096;
    float* hs  = smem + 8192;
    float* bs  = smem + 8192 + 4352;
    const int t = threadIdx.x;
    for (int i = t * 4; i < 4096; i += 1024) {
        *(float4*)&wsl[i] = *(const float4*)&Wl[i];
        *(float4*)&wsr[i] = *(const float4*)&Wr[i];
    }
    if (t < 16) *(float4*)&bs[t * 4] = *(const float4*)&bias[t * 4];
    const int dg = t & 15;
    const int r0 = t >> 4;
    for (int ph = 0; ph < 2; ++ph) {
        const int base = bid * 128 + ph * 64;
        if (base >= n) break;
        __syncthreads();   // W ready (ph0) / previous phase's hs reads done
        stage_rows(hs, H, base, n, t);
        __syncthreads();
        float4 accl[4] = {{0,0,0,0},{0,0,0,0},{0,0,0,0},{0,0,0,0}};
        float4 accr[4] = {{0,0,0,0},{0,0,0,0},{0,0,0,0},{0,0,0,0}};
#pragma unroll 4
        for (int kq = 0; kq < 16; ++kq) {
            float4 wl[4], wr[4];
#pragma unroll
            for (int i = 0; i < 4; ++i) {
                wl[i] = *(const float4*)&wsl[(kq * 4 + i) * 64 + dg * 4];
                wr[i] = *(const float4*)&wsr[(kq * 4 + i) * 64 + dg * 4];
            }
#pragma unroll
            for (int p = 0; p < 4; ++p) {
                float4 hv = *(const float4*)&hs[(r0 + p * 16) * 68 + kq * 4];
                fma4(accl[p], hv.x, wl[0]); fma4(accl[p], hv.y, wl[1]);
                fma4(accl[p], hv.z, wl[2]); fma4(accl[p], hv.w, wl[3]);
                fma4(accr[p], hv.x, wr[0]); fma4(accr[p], hv.y, wr[1]);
                fma4(accr[p], hv.z, wr[2]); fma4(accr[p], hv.w, wr[3]);
            }
        }
        float4 b4 = *(const float4*)&bs[dg * 4];
#pragma unroll
        for (int p = 0; p < 4; ++p) {
            int row = base + r0 + p * 16;
            if (row < n) {
                union { __half2 h[2]; float2 f; } u;
                u.h[0] = __floats2half2_rn(accl[p].x, accl[p].y);
                u.h[1] = __floats2half2_rn(accl[p].z, accl[p].w);
                *(float2*)&A[(size_t)row * 64 + dg * 4] = u.f;
                union { __half2 h[2]; float2 f; } v;
                v.h[0] = __floats2half2_rn(accr[p].x + b4.x, accr[p].y + b4.y);
                v.h[1] = __floats2half2_rn(accr[p].z + b4.z, accr[p].w + b4.w);
                *(float2*)&Dbuf[(size_t)row * 64 + dg * 4] = v.f;
            }
        }
    }
}

// ---- fused dispatch: blocks [0,pb) partition edges, blocks [pb,..) gemm ----
__global__ __launch_bounds__(256) void part_gemm_kernel(const int* __restrict__ src,
                                                        const int* __restrict__ dst,
                                                        int* __restrict__ gcur,
                                                        unsigned* __restrict__ P,
                                                        int nE, int nbuck, int pb,
                                                        const float* __restrict__ H,
                                                        const float* __restrict__ Wl,
                                                        const float* __restrict__ Wr,
                                                        const float* __restrict__ bias,
                                                        __half* __restrict__ A,
                                                        __half* __restrict__ Dbuf, int n) {
    __shared__ float smem[GEMM_SMEM];
    if ((int)blockIdx.x < pb) {
        int* hist = (int*)smem;
        const int t = threadIdx.x;
        for (int k = t; k < nbuck; k += 256) hist[k] = 0;
        __syncthreads();
        const int base = blockIdx.x * CHUNK;
        const int end = min(nE, base + CHUNK);
        for (int i = base + t; i < end; i += 256)
            atomicAdd(&hist[dst[i] >> 6], 1);
        __syncthreads();
        for (int k = t; k < nbuck; k += 256) {
            int h = hist[k];
            hist[k] = h ? atomicAdd(&gcur[k], h) : 0;
        }
        __syncthreads();
        for (int i = base + t; i < end; i += 256) {
            int d = dst[i];
            int bk = d >> 6;
            int pos = atomicAdd(&hist[bk], 1);
            P[pos] = ((unsigned)src[i] << 6) | (unsigned)(d & 63);
        }
    } else {
        gemm_body(blockIdx.x - pb, smem, H, Wl, Wr, bias, A, Dbuf, n);
    }
}

// ---- standalone gemm (layer 2, fp16 input) ----
__global__ __launch_bounds__(256) void gemm_kernel(const __half* __restrict__ H,
                                                   const float* __restrict__ Wl,
                                                   const float* __restrict__ Wr,
                                                   const float* __restrict__ bias,
                                                   __half* __restrict__ A,
                                                   __half* __restrict__ Dbuf, int n) {
    __shared__ float smem[GEMM_SMEM];
    gemm_body(blockIdx.x, smem, H, Wl, Wr, bias, A, Dbuf, n);
}

// ---- gather with fused in-LDS bucket sort; out = act(mean + D) ----
template <bool RELU, typename OutT>
__global__ __launch_bounds__(256) void gather_sort_combine(const __half* __restrict__ A,
                                                           const __half* __restrict__ Dbuf,
                                                           const int* __restrict__ boff,
                                                           const unsigned* __restrict__ P,
                                                           int* __restrict__ spill,
                                                           OutT* __restrict__ out, int n) {
    __shared__ int hist[BN];
    __shared__ int rstart[BN];
    __shared__ int cur[BN];
    __shared__ int lsrc[GCAP];
    const int t = threadIdx.x;
    const int b = blockIdx.x;
    if (t < BN) hist[t] = 0;
    __syncthreads();
    const int start = boff[b], end = boff[b + 1];
    const int m = end - start;
    for (int i = start + t; i < end; i += 256)
        atomicAdd(&hist[P[i] & 63], 1);
    __syncthreads();
    if (t < 64) {   // wave 0: exclusive scan of 64 counts via shuffles
        int v = hist[t];
        int s = v;
#pragma unroll
        for (int d = 1; d < 64; d <<= 1) {
            int u = __shfl_up(s, d);
            if (t >= d) s += u;
        }
        rstart[t] = s - v;
        cur[t] = s - v;
    }
    __syncthreads();
    int* list = (m <= GCAP) ? (int*)lsrc : (spill + start);
    for (int i = start + t; i < end; i += 256) {
        unsigned p = P[i];
        int pos = atomicAdd(&cur[p & 63], 1);
        list[pos] = (int)(p >> 6);
    }
    __syncthreads();
    const int dg = t & 7;
    const size_t doff = (size_t)dg * 8;
    for (int pass = 0; pass < 2; ++pass) {
        const int r = pass * 32 + (t >> 3);
        const int node = b * BN + r;
        if (node >= n) continue;
        const int c = hist[r];
        const int* sp = list + rstart[r];
        float acc[8] = {0.f, 0.f, 0.f, 0.f, 0.f, 0.f, 0.f, 0.f};
        int j = 0;
        for (; j + 4 <= c; j += 4) {
            int e0 = sp[j + 0], e1 = sp[j + 1], e2 = sp[j + 2], e3 = sp[j + 3];
            float4 r0 = *(const float4*)&A[(size_t)e0 * 64 + doff];
            float4 r1 = *(const float4*)&A[(size_t)e1 * 64 + doff];
            float4 r2 = *(const float4*)&A[(size_t)e2 * 64 + doff];
            float4 r3 = *(const float4*)&A[(size_t)e3 * 64 + doff];
            addh8(acc, r0); addh8(acc, r1); addh8(acc, r2); addh8(acc, r3);
        }
        for (; j < c; ++j) {
            float4 rr = *(const float4*)&A[(size_t)sp[j] * 64 + doff];
            addh8(acc, rr);
        }
        const float inv = 1.0f / fmaxf((float)c, 1.0f);
        float d8[8] = {0,0,0,0,0,0,0,0};
        addh8(d8, *(const float4*)&Dbuf[(size_t)node * 64 + doff]);   // D fp16 -> f32
        float o[8];
#pragma unroll
        for (int k = 0; k < 8; ++k) {
            float v = fmaf(acc[k], inv, d8[k]);
            o[k] = RELU ? fmaxf(v, 0.f) : v;
        }
        if constexpr (sizeof(OutT) == 2) {
            union { __half2 h[4]; float4 f; } u;
#pragma unroll
            for (int k = 0; k < 4; ++k)
                u.h[k] = __floats2half2_rn(o[2 * k], o[2 * k + 1]);
            *(float4*)&out[(size_t)node * 64 + doff] = u.f;
        } else {
            *(float4*)&out[(size_t)node * 64 + doff]     = make_float4(o[0], o[1], o[2], o[3]);
            *(float4*)&out[(size_t)node * 64 + doff + 4] = make_float4(o[4], o[5], o[6], o[7]);
        }
    }
}

extern "C" void kernel_launch(void* const* d_in, const int* in_sizes, int n_in,
                              void* d_out, int out_size, void* d_ws, size_t ws_size,
                              hipStream_t stream) {
    const float* x   = (const float*)d_in[0];
    const int*   ei  = (const int*)d_in[1];
    const float* w1l = (const float*)d_in[2];
    const float* b1l = (const float*)d_in[3];
    const float* w1r = (const float*)d_in[4];
    const float* w2l = (const float*)d_in[5];
    const float* b2l = (const float*)d_in[6];
    const float* w2r = (const float*)d_in[7];
    float* out = (float*)d_out;

    const int N = in_sizes[0] / DIM;   // 100000
    const int E = in_sizes[1] / 2;     // 1600000
    const int* src = ei;
    const int* dst = ei + E;
    const int nbuck = (N + BN - 1) / BN;           // 1563
    const int pb = (E + CHUNK - 1) / CHUNK;        // 196
    const int gb = (N + 127) / 128;                // 782

    // ws: ghist[nbuck] | boff[nbuck+1] | gcur[nbuck] | P[E] | spill[E] |
    //     (align 16) A fp16[N*64] | D fp16[N*64] | h1 fp16[N*64]
    int* ghist = (int*)d_ws;
    int* boff = ghist + nbuck;
    int* gcur = boff + nbuck + 1;
    unsigned* P = (unsigned*)(gcur + nbuck);
    int* spill = (int*)(P + E);
    uintptr_t ap = (uintptr_t)(spill + E);
    ap = (ap + 15) & ~(uintptr_t)15;
    __half* A  = (__half*)ap;
    __half* D  = A + (size_t)N * DIM;
    __half* h1 = D + (size_t)N * DIM;

    // ---- build + layer-1 gemm (fused) ----
    hipMemsetAsync(ghist, 0, nbuck * sizeof(int), stream);
    prehist_kernel<<<pb, 256, 0, stream>>>(dst, ghist, E, nbuck);
    scan_kernel<<<1, 1024, 0, stream>>>(ghist, boff, gcur, nbuck);
    part_gemm_kernel<<<pb + gb, 256, 0, stream>>>(src, dst, gcur, P, E, nbuck, pb,
                                                  x, w1l, w1r, b1l, A, D, N);

    // ---- layer 1 gather ----
    gather_sort_combine<true, __half><<<nbuck, 256, 0, stream>>>(A, D, boff, P, spill, h1, N);

    // ---- layer 2 ----
    gemm_kernel<<<gb, 256, 0, stream>>>(h1, w2l, w2r, b2l, A, D, N);
    gather_sort_combine<false, float><<<nbuck, 256, 0, stream>>>(A, D, boff, P, spill, out, N);
}

// Round 9
// 271.194 us; speedup vs baseline: 1.2817x; 1.0698x over previous
//
#include <hip/hip_runtime.h>
#include <hip/hip_fp16.h>

// GraphSAGE 2-layer encoder — R9: MFMA GEMMs.
// R8 postmortem: part_gemm 65us, occupancy 15% (50KB fp32 LDS -> 3 blocks/CU),
// VALU-ALU matmul at ~25TF. R9 computes both tables with
// v_mfma_f32_16x16x32_f16, transposed so n=node: A-operand = W^T (staged fp16
// LDS, 18KB), B-operand = H row fragments (one 16B contiguous load/lane), C/D
// epilogue = one 8B store of 4 consecutive dims per tile. Gather kernels
// unchanged (near the L2-miss-path floor: 161MB @ ~3.5TB/s).

#define DIM 64
#define BN 64                 // nodes per bucket (dst >> 6)
#define MAXBUCK 2048          // LDS bound (nbuck = 1563)
#define CHUNK 8192            // edges per hist/partition block
#define GCAP 2048             // LDS edge capacity per gather block
#define WT_STRIDE 72          // padded k-stride of W^T in LDS (halves)

using f16x8 = __attribute__((ext_vector_type(8))) _Float16;
using f32x4 = __attribute__((ext_vector_type(4))) float;

// accumulate 8 halves (float4 bit-pattern) into acc[8]
__device__ inline void addh8(float* acc, float4 raw) {
    const __half2* hp = (const __half2*)&raw;
#pragma unroll
    for (int k = 0; k < 4; ++k) {
        float2 f = __half22float2(hp[k]);
        acc[2 * k]     += f.x;
        acc[2 * k + 1] += f.y;
    }
}

// ---- pre-histogram: global bucket counts ----
__global__ __launch_bounds__(256) void prehist_kernel(const int* __restrict__ dst,
                                                      int* __restrict__ ghist,
                                                      int nE, int nbuck) {
    __shared__ int hist[MAXBUCK];
    const int t = threadIdx.x;
    for (int k = t; k < nbuck; k += 256) hist[k] = 0;
    __syncthreads();
    const int base = blockIdx.x * CHUNK;
    const int end = min(nE, base + CHUNK);
    for (int i = base + t; i < end; i += 256)
        atomicAdd(&hist[dst[i] >> 6], 1);
    __syncthreads();
    for (int k = t; k < nbuck; k += 256)
        if (hist[k]) atomicAdd(&ghist[k], hist[k]);
}

// ---- exclusive scan of bucket totals (1 block, up to 2048) -> boff, gcur ----
__global__ __launch_bounds__(1024) void scan_kernel(const int* __restrict__ ghist,
                                                    int* __restrict__ boff,
                                                    int* __restrict__ gcur, int nbuck) {
    __shared__ int sa[2048], sb[2048];
    const int t = threadIdx.x;
    int v0 = (t < nbuck) ? ghist[t] : 0;
    int v1 = (t + 1024 < nbuck) ? ghist[t + 1024] : 0;
    sa[t] = v0; sa[t + 1024] = v1;
    __syncthreads();
    int* in = sa; int* out = sb;
    for (int d = 1; d < 2048; d <<= 1) {
        out[t] = in[t] + ((t >= d) ? in[t - d] : 0);
        int i2 = t + 1024;
        out[i2] = in[i2] + ((i2 >= d) ? in[i2 - d] : 0);
        __syncthreads();
        int* tmp = in; in = out; out = tmp;
    }
    if (t < nbuck) { int e = in[t] - v0; boff[t] = e; gcur[t] = e; }
    if (t + 1024 < nbuck) { int e = in[t + 1024] - v1; boff[t + 1024] = e; gcur[t + 1024] = e; }
    if (t == 0) boff[nbuck] = in[2047];
}

// ---- B-fragment loaders: lane's node row, k = ki*32 + quad*8 + j ----
__device__ inline void load_bfrag(const __half* __restrict__ H, long long nn, int lq,
                                  f16x8& b0, f16x8& b1) {
    b0 = *(const f16x8*)&H[nn * 64 + lq * 8];
    b1 = *(const f16x8*)&H[nn * 64 + 32 + lq * 8];
}
__device__ inline void load_bfrag(const float* __restrict__ H, long long nn, int lq,
                                  f16x8& b0, f16x8& b1) {
    const float* p = &H[nn * 64 + lq * 8];
    float4 u0 = *(const float4*)p;
    float4 u1 = *(const float4*)(p + 4);
    float4 u2 = *(const float4*)(p + 32);
    float4 u3 = *(const float4*)(p + 36);
    b0[0] = (_Float16)u0.x; b0[1] = (_Float16)u0.y; b0[2] = (_Float16)u0.z; b0[3] = (_Float16)u0.w;
    b0[4] = (_Float16)u1.x; b0[5] = (_Float16)u1.y; b0[6] = (_Float16)u1.z; b0[7] = (_Float16)u1.w;
    b1[0] = (_Float16)u2.x; b1[1] = (_Float16)u2.y; b1[2] = (_Float16)u2.z; b1[3] = (_Float16)u2.w;
    b1[4] = (_Float16)u3.x; b1[5] = (_Float16)u3.y; b1[6] = (_Float16)u3.z; b1[7] = (_Float16)u3.w;
}

// ---- MFMA dual-GEMM body: A(fp16)=H@Wl ; D(fp16)=H@Wr+bias; 256 nodes/block.
// Computes transposed tiles: D[m][n], n = node (C/D col), m = out-dim.
template <typename InT>
__device__ void gemm_body(int bid, __half* wt,
                          const InT* __restrict__ H,
                          const float* __restrict__ Wl, const float* __restrict__ Wr,
                          const float* __restrict__ bias,
                          __half* __restrict__ A, __half* __restrict__ Dbuf, int n) {
    const int t = threadIdx.x;
    // stage W^T (fp16): wt[(mat*64 + m)*WT_STRIDE + k] = W[k][m]
    for (int i = t; i < 4096; i += 256) {
        int k = i >> 6, m = i & 63;
        wt[(size_t)m * WT_STRIDE + k] = __float2half(Wl[i]);
        wt[(size_t)(64 + m) * WT_STRIDE + k] = __float2half(Wr[i]);
    }
    __syncthreads();
    const int lane = t & 63, wave = t >> 6;
    const int ln = lane & 15, lq = lane >> 4;
    // A-operand frags (persist across all node tiles)
    f16x8 af[2][4][2];
#pragma unroll
    for (int mat = 0; mat < 2; ++mat)
#pragma unroll
        for (int mt = 0; mt < 4; ++mt)
#pragma unroll
            for (int ki = 0; ki < 2; ++ki)
                af[mat][mt][ki] = *(const f16x8*)&wt[(size_t)(mat * 64 + mt * 16 + ln) * WT_STRIDE
                                                     + ki * 32 + lq * 8];
    float4 bf[4];
#pragma unroll
    for (int mt = 0; mt < 4; ++mt)
        bf[mt] = *(const float4*)&bias[mt * 16 + lq * 4];

    const int base = bid * 256;
    for (int it = 0; it < 4; ++it) {
        const int node = base + it * 64 + wave * 16 + ln;
        const long long nn = (node < n) ? node : (n - 1);
        f16x8 b0, b1;
        load_bfrag(H, nn, lq, b0, b1);
        f32x4 acc[2][4];
#pragma unroll
        for (int mat = 0; mat < 2; ++mat)
#pragma unroll
            for (int mt = 0; mt < 4; ++mt) {
                f32x4 z = {0.f, 0.f, 0.f, 0.f};
                z = __builtin_amdgcn_mfma_f32_16x16x32_f16(af[mat][mt][0], b0, z, 0, 0, 0);
                z = __builtin_amdgcn_mfma_f32_16x16x32_f16(af[mat][mt][1], b1, z, 0, 0, 0);
                acc[mat][mt] = z;
            }
        if (node < n) {
#pragma unroll
            for (int mt = 0; mt < 4; ++mt) {
                union { __half2 h[2]; float2 f; } u;
                u.h[0] = __floats2half2_rn(acc[0][mt][0], acc[0][mt][1]);
                u.h[1] = __floats2half2_rn(acc[0][mt][2], acc[0][mt][3]);
                *(float2*)&A[(size_t)node * 64 + mt * 16 + lq * 4] = u.f;
                union { __half2 h[2]; float2 f; } v;
                v.h[0] = __floats2half2_rn(acc[1][mt][0] + bf[mt].x, acc[1][mt][1] + bf[mt].y);
                v.h[1] = __floats2half2_rn(acc[1][mt][2] + bf[mt].z, acc[1][mt][3] + bf[mt].w);
                *(float2*)&Dbuf[(size_t)node * 64 + mt * 16 + lq * 4] = v.f;
            }
        }
    }
}

// ---- fused dispatch: blocks [0,pb) partition edges, blocks [pb,..) gemm ----
__global__ __launch_bounds__(256) void part_gemm_kernel(const int* __restrict__ src,
                                                        const int* __restrict__ dst,
                                                        int* __restrict__ gcur,
                                                        unsigned* __restrict__ P,
                                                        int nE, int nbuck, int pb,
                                                        const float* __restrict__ H,
                                                        const float* __restrict__ Wl,
                                                        const float* __restrict__ Wr,
                                                        const float* __restrict__ bias,
                                                        __half* __restrict__ A,
                                                        __half* __restrict__ Dbuf, int n) {
    __shared__ __align__(16) unsigned short smem_u[2 * 64 * WT_STRIDE];  // 18KB; >= 8KB hist
    if ((int)blockIdx.x < pb) {
        int* hist = (int*)smem_u;
        const int t = threadIdx.x;
        for (int k = t; k < nbuck; k += 256) hist[k] = 0;
        __syncthreads();
        const int base = blockIdx.x * CHUNK;
        const int end = min(nE, base + CHUNK);
        for (int i = base + t; i < end; i += 256)
            atomicAdd(&hist[dst[i] >> 6], 1);
        __syncthreads();
        for (int k = t; k < nbuck; k += 256) {
            int h = hist[k];
            hist[k] = h ? atomicAdd(&gcur[k], h) : 0;
        }
        __syncthreads();
        for (int i = base + t; i < end; i += 256) {
            int d = dst[i];
            int bk = d >> 6;
            int pos = atomicAdd(&hist[bk], 1);
            P[pos] = ((unsigned)src[i] << 6) | (unsigned)(d & 63);
        }
    } else {
        gemm_body(blockIdx.x - pb, (__half*)smem_u, H, Wl, Wr, bias, A, Dbuf, n);
    }
}

// ---- standalone gemm (layer 2, fp16 input) ----
__global__ __launch_bounds__(256) void gemm_kernel(const __half* __restrict__ H,
                                                   const float* __restrict__ Wl,
                                                   const float* __restrict__ Wr,
                                                   const float* __restrict__ bias,
                                                   __half* __restrict__ A,
                                                   __half* __restrict__ Dbuf, int n) {
    __shared__ __align__(16) unsigned short smem_u[2 * 64 * WT_STRIDE];
    gemm_body(blockIdx.x, (__half*)smem_u, H, Wl, Wr, bias, A, Dbuf, n);
}

// ---- gather with fused in-LDS bucket sort; out = act(mean + D) ----
template <bool RELU, typename OutT>
__global__ __launch_bounds__(256) void gather_sort_combine(const __half* __restrict__ A,
                                                           const __half* __restrict__ Dbuf,
                                                           const int* __restrict__ boff,
                                                           const unsigned* __restrict__ P,
                                                           int* __restrict__ spill,
                                                           OutT* __restrict__ out, int n) {
    __shared__ int hist[BN];
    __shared__ int rstart[BN];
    __shared__ int cur[BN];
    __shared__ int lsrc[GCAP];
    const int t = threadIdx.x;
    const int b = blockIdx.x;
    if (t < BN) hist[t] = 0;
    __syncthreads();
    const int start = boff[b], end = boff[b + 1];
    const int m = end - start;
    for (int i = start + t; i < end; i += 256)
        atomicAdd(&hist[P[i] & 63], 1);
    __syncthreads();
    if (t < 64) {   // wave 0: exclusive scan of 64 counts via shuffles
        int v = hist[t];
        int s = v;
#pragma unroll
        for (int d = 1; d < 64; d <<= 1) {
            int u = __shfl_up(s, d);
            if (t >= d) s += u;
        }
        rstart[t] = s - v;
        cur[t] = s - v;
    }
    __syncthreads();
    int* list = (m <= GCAP) ? (int*)lsrc : (spill + start);
    for (int i = start + t; i < end; i += 256) {
        unsigned p = P[i];
        int pos = atomicAdd(&cur[p & 63], 1);
        list[pos] = (int)(p >> 6);
    }
    __syncthreads();
    const int dg = t & 7;
    const size_t doff = (size_t)dg * 8;
    for (int pass = 0; pass < 2; ++pass) {
        const int r = pass * 32 + (t >> 3);
        const int node = b * BN + r;
        if (node >= n) continue;
        const int c = hist[r];
        const int* sp = list + rstart[r];
        float acc[8] = {0.f, 0.f, 0.f, 0.f, 0.f, 0.f, 0.f, 0.f};
        int j = 0;
        for (; j + 4 <= c; j += 4) {
            int e0 = sp[j + 0], e1 = sp[j + 1], e2 = sp[j + 2], e3 = sp[j + 3];
            float4 r0 = *(const float4*)&A[(size_t)e0 * 64 + doff];
            float4 r1 = *(const float4*)&A[(size_t)e1 * 64 + doff];
            float4 r2 = *(const float4*)&A[(size_t)e2 * 64 + doff];
            float4 r3 = *(const float4*)&A[(size_t)e3 * 64 + doff];
            addh8(acc, r0); addh8(acc, r1); addh8(acc, r2); addh8(acc, r3);
        }
        for (; j < c; ++j) {
            float4 rr = *(const float4*)&A[(size_t)sp[j] * 64 + doff];
            addh8(acc, rr);
        }
        const float inv = 1.0f / fmaxf((float)c, 1.0f);
        float d8[8] = {0, 0, 0, 0, 0, 0, 0, 0};
        addh8(d8, *(const float4*)&Dbuf[(size_t)node * 64 + doff]);
        float o[8];
#pragma unroll
        for (int k = 0; k < 8; ++k) {
            float v = fmaf(acc[k], inv, d8[k]);
            o[k] = RELU ? fmaxf(v, 0.f) : v;
        }
        if constexpr (sizeof(OutT) == 2) {
            union { __half2 h[4]; float4 f; } u;
#pragma unroll
            for (int k = 0; k < 4; ++k)
                u.h[k] = __floats2half2_rn(o[2 * k], o[2 * k + 1]);
            *(float4*)&out[(size_t)node * 64 + doff] = u.f;
        } else {
            *(float4*)&out[(size_t)node * 64 + doff]     = make_float4(o[0], o[1], o[2], o[3]);
            *(float4*)&out[(size_t)node * 64 + doff + 4] = make_float4(o[4], o[5], o[6], o[7]);
        }
    }
}

extern "C" void kernel_launch(void* const* d_in, const int* in_sizes, int n_in,
                              void* d_out, int out_size, void* d_ws, size_t ws_size,
                              hipStream_t stream) {
    const float* x   = (const float*)d_in[0];
    const int*   ei  = (const int*)d_in[1];
    const float* w1l = (const float*)d_in[2];
    const float* b1l = (const float*)d_in[3];
    const float* w1r = (const float*)d_in[4];
    const float* w2l = (const float*)d_in[5];
    const float* b2l = (const float*)d_in[6];
    const float* w2r = (const float*)d_in[7];
    float* out = (float*)d_out;

    const int N = in_sizes[0] / DIM;   // 100000
    const int E = in_sizes[1] / 2;     // 1600000
    const int* src = ei;
    const int* dst = ei + E;
    const int nbuck = (N + BN - 1) / BN;           // 1563
    const int pb = (E + CHUNK - 1) / CHUNK;        // 196
    const int gb = (N + 255) / 256;                // 391

    // ws: ghist[nbuck] | boff[nbuck+1] | gcur[nbuck] | P[E] | spill[E] |
    //     (align 16) A fp16[N*64] | D fp16[N*64] | h1 fp16[N*64]
    int* ghist = (int*)d_ws;
    int* boff = ghist + nbuck;
    int* gcur = boff + nbuck + 1;
    unsigned* P = (unsigned*)(gcur + nbuck);
    int* spill = (int*)(P + E);
    uintptr_t ap = (uintptr_t)(spill + E);
    ap = (ap + 15) & ~(uintptr_t)15;
    __half* A  = (__half*)ap;
    __half* D  = A + (size_t)N * DIM;
    __half* h1 = D + (size_t)N * DIM;

    // ---- build + layer-1 gemm (fused) ----
    hipMemsetAsync(ghist, 0, nbuck * sizeof(int), stream);
    prehist_kernel<<<pb, 256, 0, stream>>>(dst, ghist, E, nbuck);
    scan_kernel<<<1, 1024, 0, stream>>>(ghist, boff, gcur, nbuck);
    part_gemm_kernel<<<pb + gb, 256, 0, stream>>>(src, dst, gcur, P, E, nbuck, pb,
                                                  x, w1l, w1r, b1l, A, D, N);

    // ---- layer 1 gather ----
    gather_sort_combine<true, __half><<<nbuck, 256, 0, stream>>>(A, D, boff, P, spill, h1, N);

    // ---- layer 2 ----
    gemm_kernel<<<gb, 256, 0, stream>>>(h1, w2l, w2r, b2l, A, D, N);
    gather_sort_combine<false, float><<<nbuck, 256, 0, stream>>>(A, D, boff, P, spill, out, N);
}